// Round 11
// baseline (4175.426 us; speedup 1.0000x reference)
//
#include <hip/hip_runtime.h>
#include <math.h>

#define N 2048
#define CAP (1u << 20)
#define ECAP 520192u  // (4MB - 32KB) / 8 bytes per edge

typedef unsigned int uint;
typedef unsigned short ushort;
typedef unsigned long long ull;

// ws layout (big): [0] counter | [64] ecursor | [128] eflag | [256] prep 128KB |
// [131328] pairs 4MB (reused after interB: edges u64[ECAP] + rowptr/rowcnt 16KB) | W 16MB
#define PREP_OFF  256
#define PAIRS_OFF (PREP_OFF + 131072)
#define RPTR_OFF  (PAIRS_OFF + (size_t)ECAP * 8)
#define RCNT_OFF  (RPTR_OFF + 8192)
#define W_OFF_BIG (PAIRS_OFF + (size_t)CAP * 4)
#define NEED_BIG  (W_OFF_BIG + 16777216ull)
#define W_OFF_SMALL PAIRS_OFF
#define NEED_SMALL  (W_OFF_SMALL + 16777216ull)

// ---------- DPP wave-64 reductions ----------
__device__ __forceinline__ float wave_max_f32_bcast(float v) {
  int x = __float_as_int(v);
  const int ID = 0xFF800000;  // -inf
  int t;
  t = __builtin_amdgcn_update_dpp(ID, x, 0x111, 0xF, 0xF, false);
  x = __float_as_int(fmaxf(__int_as_float(x), __int_as_float(t)));
  t = __builtin_amdgcn_update_dpp(ID, x, 0x112, 0xF, 0xF, false);
  x = __float_as_int(fmaxf(__int_as_float(x), __int_as_float(t)));
  t = __builtin_amdgcn_update_dpp(ID, x, 0x114, 0xF, 0xF, false);
  x = __float_as_int(fmaxf(__int_as_float(x), __int_as_float(t)));
  t = __builtin_amdgcn_update_dpp(ID, x, 0x118, 0xF, 0xF, false);
  x = __float_as_int(fmaxf(__int_as_float(x), __int_as_float(t)));
  t = __builtin_amdgcn_update_dpp(ID, x, 0x142, 0xF, 0xF, false);
  x = __float_as_int(fmaxf(__int_as_float(x), __int_as_float(t)));
  t = __builtin_amdgcn_update_dpp(ID, x, 0x143, 0xF, 0xF, false);
  x = __float_as_int(fmaxf(__int_as_float(x), __int_as_float(t)));
  x = __builtin_amdgcn_readlane(x, 63);
  return __int_as_float(x);
}
__device__ __forceinline__ int wave_min_i32_bcast(int v) {
  const int ID = 0x7FFFFFFF;
  int t;
  t = __builtin_amdgcn_update_dpp(ID, v, 0x111, 0xF, 0xF, false); v = min(v, t);
  t = __builtin_amdgcn_update_dpp(ID, v, 0x112, 0xF, 0xF, false); v = min(v, t);
  t = __builtin_amdgcn_update_dpp(ID, v, 0x114, 0xF, 0xF, false); v = min(v, t);
  t = __builtin_amdgcn_update_dpp(ID, v, 0x118, 0xF, 0xF, false); v = min(v, t);
  t = __builtin_amdgcn_update_dpp(ID, v, 0x142, 0xF, 0xF, false); v = min(v, t);
  t = __builtin_amdgcn_update_dpp(ID, v, 0x143, 0xF, 0xF, false); v = min(v, t);
  return __builtin_amdgcn_readlane(v, 63);
}

// Per-box precompute + counters zero.
__global__ __launch_bounds__(256) void prep_kernel(const float* __restrict__ boxes,
                                                   float* __restrict__ prep,
                                                   uint* __restrict__ ctrs) {
#pragma clang fp contract(off)
  int i = blockIdx.x * 256 + threadIdx.x;
  if (blockIdx.x == 0 && threadIdx.x < 3) ctrs[threadIdx.x * 16] = 0u;  // counter/ecursor/eflag
  if (i >= N) return;
  float xc = boxes[i * 5 + 0], yc = boxes[i * 5 + 1];
  float w = boxes[i * 5 + 2], h = boxes[i * 5 + 3], th = boxes[i * 5 + 4];
  float t = th * 0.017453292519943295f;
  float c = (float)cos((double)t);
  float s = (float)sin((double)t);
  float w2 = w * 0.5f, h2 = h * 0.5f;
  float lx[4] = {-w2, w2, w2, -w2};
  float ly[4] = {-h2, -h2, h2, h2};
  float* P = prep + i * 16;
#pragma unroll
  for (int k = 0; k < 4; k++) {
    P[k * 2 + 0] = (xc + lx[k] * c) - ly[k] * s;
    P[k * 2 + 1] = (yc + lx[k] * s) + ly[k] * c;
  }
  P[8] = xc; P[9] = yc; P[10] = c; P[11] = s; P[12] = w2; P[13] = h2;
  P[14] = w * h;
  P[15] = sqrtf(w2 * w2 + h2 * h2);
}

// Bounding-circle filter; rejected pairs write W=1.0 (exact); survivors compacted.
__global__ __launch_bounds__(256) void pairs_kernel(const float* __restrict__ prep,
                                                    uint* __restrict__ pairs,
                                                    uint* __restrict__ counter,
                                                    float* __restrict__ W) {
  uint gid = blockIdx.x * 256u + threadIdx.x;
  uint i = gid >> 11, j = gid & 2047u;
  const float* Pi = prep + i * 16;
  const float* Pj = prep + j * 16;
  float dx = Pi[8] - Pj[8], dy = Pi[9] - Pj[9];
  float rr = Pi[15] + Pj[15] + 1.0f;
  bool keep = (dx * dx + dy * dy) <= rr * rr;
  if (!keep) W[(size_t)i * N + j] = 1.0f;
  ull m = __ballot(keep);
  if (m == 0ull) return;
  int lane = (int)(threadIdx.x & 63u);
  int leader = __ffsll((long long)m) - 1;
  uint base = 0;
  if (lane == leader) base = atomicAdd(counter, (uint)__popcll(m));
  base = (uint)__shfl((int)base, leader);
  if (keep) {
    uint pos = base + (uint)__popcll(m & ((1ull << lane) - 1ull));
    if (pos < CAP) pairs[pos] = (i << 11) | j;
    else W[(size_t)i * N + j] = 1.0f;
  }
}

// Rotated-rect intersection weight, op-for-op fp32 mirror of the reference.
__device__ float pair_weight(const float* __restrict__ Pi, const float* __restrict__ Pj) {
#pragma clang fp contract(off)
  float ax[4], ay[4], bx[4], by[4];
#pragma unroll
  for (int k = 0; k < 4; k++) {
    ax[k] = Pi[2 * k]; ay[k] = Pi[2 * k + 1];
    bx[k] = Pj[2 * k]; by[k] = Pj[2 * k + 1];
  }
  float ptsx[24], ptsy[24];
  bool msk[24];
#pragma unroll
  for (int e = 0; e < 4; e++) {
    float Ax = ax[e], Ay = ay[e];
    float BAx = ax[(e + 1) & 3] - Ax, BAy = ay[(e + 1) & 3] - Ay;
#pragma unroll
    for (int f = 0; f < 4; f++) {
      float Cx = bx[f], Cy = by[f];
      float DCx = bx[(f + 1) & 3] - Cx, DCy = by[(f + 1) & 3] - Cy;
      float CAx = Cx - Ax, CAy = Cy - Ay;
      float den = BAx * DCy - BAy * DCx;
      bool dok = fabsf(den) > 1e-12f;
      float dens = dok ? den : 1.0f;
      float t = (CAx * DCy - CAy * DCx) / dens;
      float u = (CAx * BAy - CAy * BAx) / dens;
      int id = e * 4 + f;
      ptsx[id] = Ax + t * BAx;
      ptsy[id] = Ay + t * BAy;
      msk[id] = dok && (t >= 0.0f) && (t <= 1.0f) && (u >= 0.0f) && (u <= 1.0f);
    }
  }
  float xcj = Pj[8], ycj = Pj[9], cj = Pj[10], sj = Pj[11], w2j = Pj[12], h2j = Pj[13];
  float xci = Pi[8], yci = Pi[9], ci = Pi[10], si = Pi[11], w2i = Pi[12], h2i = Pi[13];
#pragma unroll
  for (int k = 0; k < 4; k++) {
    float dx = ax[k] - xcj, dy = ay[k] - ycj;
    float xl = dx * cj + dy * sj;
    float yl = -dx * sj + dy * cj;
    ptsx[16 + k] = ax[k]; ptsy[16 + k] = ay[k];
    msk[16 + k] = (fabsf(xl) <= w2j + 1e-5f) && (fabsf(yl) <= h2j + 1e-5f);
  }
#pragma unroll
  for (int k = 0; k < 4; k++) {
    float dx = bx[k] - xci, dy = by[k] - yci;
    float xl = dx * ci + dy * si;
    float yl = -dx * si + dy * ci;
    ptsx[20 + k] = bx[k]; ptsy[20 + k] = by[k];
    msk[20 + k] = (fabsf(xl) <= w2i + 1e-5f) && (fabsf(yl) <= h2i + 1e-5f);
  }
  int cnt = 0;
  float sx = 0.f, sy = 0.f;
#pragma unroll
  for (int k = 0; k < 24; k++) {
    if (msk[k]) { cnt++; sx += ptsx[k]; sy += ptsy[k]; }
  }
  float fc = (float)(cnt > 1 ? cnt : 1);
  float ctx = sx / fc, cty = sy / fc;
  float ang[32], px[32], py[32];
  int idp[32];
#pragma unroll
  for (int k = 0; k < 24; k++) {
    float rx = ptsx[k] - ctx, ry = ptsy[k] - cty;
    px[k] = rx; py[k] = ry; idp[k] = k;
    ang[k] = msk[k] ? (float)atan2((double)ry, (double)rx) : 1.0e3f;
  }
#pragma unroll
  for (int k = 24; k < 32; k++) { ang[k] = 1.0e30f; px[k] = 0.f; py[k] = 0.f; idp[k] = k; }
#pragma unroll
  for (int k = 2; k <= 32; k <<= 1) {
#pragma unroll
    for (int j = k >> 1; j > 0; j >>= 1) {
#pragma unroll
      for (int x = 0; x < 32; x++) {
        int l = x ^ j;
        if (l > x) {
          bool up = ((x & k) == 0);
          bool gt = (ang[x] > ang[l]) || (ang[x] == ang[l] && idp[x] > idp[l]);
          if (gt == up) {
            float t0 = ang[x]; ang[x] = ang[l]; ang[l] = t0;
            float t1 = px[x]; px[x] = px[l]; px[l] = t1;
            float t2 = py[x]; py[x] = py[l]; py[l] = t2;
            int t3 = idp[x]; idp[x] = idp[l]; idp[l] = t3;
          }
        }
      }
    }
  }
  float term[24];
#pragma unroll
  for (int x = 0; x < 24; x++) {
    int nx = (x + 1 < cnt) ? x + 1 : 0;
    float cr = px[x] * py[nx] - py[x] * px[nx];
    term[x] = (x < cnt) ? cr : 0.0f;
  }
  float r[8];
#pragma unroll
  for (int j = 0; j < 8; j++) r[j] = (term[j] + term[j + 8]) + term[j + 16];
  float ssum = ((r[0] + r[1]) + (r[2] + r[3])) + ((r[4] + r[5]) + (r[6] + r[7]));
  float area = 0.5f * fabsf(ssum);
  float inter = (cnt >= 3) ? area : 0.0f;
  float iou = inter / ((Pi[14] + Pj[14] - inter) + 1e-9f);
  return (iou > 0.3f) ? (1.0f - iou) : 1.0f;
}

__global__ __launch_bounds__(64, 2) void interB_kernel(const float* __restrict__ prep,
                                                       const uint* __restrict__ pairs,
                                                       const uint* __restrict__ counter,
                                                       float* __restrict__ W) {
  uint idx = blockIdx.x * 64u + threadIdx.x;
  uint n = *counter;
  if (n > CAP) n = CAP;
  if (idx >= n) return;
  uint pk = pairs[idx];
  uint i = pk >> 11, j = pk & 2047u;
  W[(size_t)i * N + j] = pair_weight(prep + i * 16, prep + j * 16);
}

__global__ __launch_bounds__(64, 2) void inter_dense(const float* __restrict__ prep,
                                                     float* __restrict__ W) {
  uint gid = blockIdx.x * 64u + threadIdx.x;
  uint i = gid >> 11, j = gid & 2047u;
  const float* Pi = prep + i * 16;
  const float* Pj = prep + j * 16;
  float dx = Pi[8] - Pj[8], dy = Pi[9] - Pj[9];
  float rr = Pi[15] + Pj[15] + 1.0f;
  float w = 1.0f;
  if (dx * dx + dy * dy <= rr * rr) w = pair_weight(Pi, Pj);
  W[(size_t)i * N + j] = w;
}

// Build symmetrized sparse CSR from dense W: edge (i,j) iff i!=j and
// (W[i][j]!=1 or W[j][i]!=1). Stored w = W[i][j] (=1.0 is an exact no-op on decay).
__global__ __launch_bounds__(256) void csr_build(const float* __restrict__ W,
                                                 ull* __restrict__ edges,
                                                 uint* __restrict__ rowptr,
                                                 uint* __restrict__ rowcnt,
                                                 uint* __restrict__ ecursor,
                                                 uint* __restrict__ eflag) {
  __shared__ int pre[256];
  __shared__ uint basesh;
  int i = blockIdx.x;
  int tid = threadIdx.x;
  uint cols[8]; uint wb[8];
  int cnt = 0;
#pragma unroll
  for (int c = 0; c < 8; c++) {
    int j = tid + 256 * c;
    float wij = W[(size_t)i * N + j];
    float wji = W[(size_t)j * N + i];
    if (j != i && (wij != 1.0f || wji != 1.0f)) {
      cols[cnt] = (uint)j; wb[cnt] = __float_as_uint(wij); cnt++;
    }
  }
  pre[tid] = cnt;
  __syncthreads();
  for (int d = 1; d < 256; d <<= 1) {
    int v = pre[tid];
    int add = (tid >= d) ? pre[tid - d] : 0;
    __syncthreads();
    pre[tid] = v + add;
    __syncthreads();
  }
  int total = pre[255];
  int myoff = pre[tid] - cnt;
  if (tid == 0) {
    uint base = atomicAdd(ecursor, (uint)total);
    if (base + (uint)total > ECAP) { *eflag = 1u; basesh = 0xFFFFFFFFu; }
    else basesh = base;
    rowptr[i] = (basesh == 0xFFFFFFFFu) ? 0u : basesh;
    rowcnt[i] = (uint)total;
  }
  __syncthreads();
  uint base = basesh;
  if (base != 0xFFFFFFFFu) {
    for (int t = 0; t < cnt; t++)
      edges[base + (uint)(myoff + t)] = (((ull)wb[t]) << 32) | (ull)cols[t];
  }
}

// Component-parallel soft-NMS: label propagation (LDS) -> per-component sequential
// scans (one wave each, work-stealing) -> global sort of (value desc, index asc).
// Correctness: picked values are non-increasing; decays are component-local and
// applied in identical order => bit-exact rec; sort reproduces np.argmax tie-break.
__global__ __launch_bounds__(1024) void comp_scan(const float* __restrict__ scores,
                                                  const ull* __restrict__ edges,
                                                  const uint* __restrict__ rowptr,
                                                  const uint* __restrict__ rowcnt,
                                                  const uint* __restrict__ eflag,
                                                  const float* __restrict__ W,
                                                  int force_dense,
                                                  float* __restrict__ out) {
  __shared__ float s_lds[N];
  __shared__ int lab[N];
  __shared__ int cnt_r[N];
  __shared__ int off_r[N];
  __shared__ ushort mlist[N];
  __shared__ ushort roots[N];
  __shared__ ull keys[N];
  __shared__ int nroots, chg, comp_head;
  __shared__ float rv[16];
  __shared__ int ri[16];
  int tid = threadIdx.x;
  s_lds[tid] = scores[tid];
  s_lds[tid + 1024] = scores[tid + 1024];
  bool dense = force_dense || (*eflag != 0u);
  if (dense) {
    // proven round-8 dense sequential scan (fallback only)
    lab[tid] = 0; lab[tid + 1024] = 0;
    __syncthreads();
    const float NINF = -__builtin_inff();
    for (int t = 0; t < N; ++t) {
      float v0 = lab[tid] ? NINF : s_lds[tid];
      float v1 = lab[tid + 1024] ? NINF : s_lds[tid + 1024];
      float bv; int bi;
      if (v0 >= v1) { bv = v0; bi = tid; } else { bv = v1; bi = tid + 1024; }
#pragma unroll
      for (int off = 32; off > 0; off >>= 1) {
        float ov = __shfl_down(bv, off);
        int oi = __shfl_down(bi, off);
        if (ov > bv || (ov == bv && oi < bi)) { bv = ov; bi = oi; }
      }
      if ((tid & 63) == 0) { rv[tid >> 6] = bv; ri[tid >> 6] = bi; }
      __syncthreads();
      float mv = rv[0]; int mi = ri[0];
#pragma unroll
      for (int k2 = 1; k2 < 16; k2++) {
        float ov = rv[k2]; int oi = ri[k2];
        if (ov > mv || (ov == mv && oi < mi)) { mv = ov; mi = oi; }
      }
      if (tid == 0) { out[t] = (float)mi; out[N + t] = (mv > 0.001f) ? 1.0f : 0.0f; out[2 * N + t] = mv; }
      if (tid == (mi & 1023)) lab[mi] = 1;
      if (mv > 0.001f) {
        const float* Wr = W + (size_t)mi * N;
        float w0 = Wr[tid], w1 = Wr[tid + 1024];
        if (!lab[tid]) s_lds[tid] *= w0;
        if (!lab[tid + 1024]) s_lds[tid + 1024] *= w1;
      }
      __syncthreads();
    }
    return;
  }
  lab[tid] = tid; lab[tid + 1024] = tid + 1024;
  if (tid == 0) { nroots = 0; comp_head = 0; }
  __syncthreads();
  // min-label propagation + pointer jumping until converged (monotone => terminates)
  while (true) {
    if (tid == 0) chg = 0;
    __syncthreads();
#pragma unroll
    for (int h = 0; h < 2; h++) {
      int j = tid + 1024 * h;
      int m = lab[j];
      uint base = rowptr[j], ne = rowcnt[j];
      for (uint e = 0; e < ne; e++) {
        int col = (int)(edges[base + e] & 0xFFFFFFFFull);
        int lc = lab[col];
        if (lc < m) m = lc;
      }
      if (m < lab[j]) { lab[j] = m; chg = 1; }  // races benign: monotone min
    }
    __syncthreads();
#pragma unroll
    for (int r = 0; r < 2; r++) {
#pragma unroll
      for (int h = 0; h < 2; h++) {
        int j = tid + 1024 * h;
        lab[j] = lab[lab[j]];
      }
      __syncthreads();
    }
    int done = (chg == 0);
    __syncthreads();
    if (done) break;
  }
  // component sizes / offsets / member lists / roots
  cnt_r[tid] = 0; cnt_r[tid + 1024] = 0;
  __syncthreads();
  atomicAdd(&cnt_r[lab[tid]], 1);
  atomicAdd(&cnt_r[lab[tid + 1024]], 1);
  __syncthreads();
  off_r[tid] = cnt_r[tid]; off_r[tid + 1024] = cnt_r[tid + 1024];
  __syncthreads();
  for (int d = 1; d < N; d <<= 1) {
    int a0 = off_r[tid] + ((tid >= d) ? off_r[tid - d] : 0);
    int a1 = off_r[tid + 1024] + ((tid + 1024 >= d) ? off_r[tid + 1024 - d] : 0);
    __syncthreads();
    off_r[tid] = a0; off_r[tid + 1024] = a1;
    __syncthreads();
  }
  int e0 = off_r[tid] - cnt_r[tid];
  int e1 = off_r[tid + 1024] - cnt_r[tid + 1024];
  __syncthreads();
  off_r[tid] = e0; off_r[tid + 1024] = e1;
  int* cur = (int*)keys;  // alias: dead before picks write keys
  cur[tid] = e0; cur[tid + 1024] = e1;
  if (lab[tid] == tid) { int rid = atomicAdd(&nroots, 1); roots[rid] = (ushort)tid; }
  if (lab[tid + 1024] == tid + 1024) { int rid = atomicAdd(&nroots, 1); roots[rid] = (ushort)(tid + 1024); }
  __syncthreads();
  { int p = atomicAdd(&cur[lab[tid]], 1); mlist[p] = (ushort)tid; }
  { int p = atomicAdd(&cur[lab[tid + 1024]], 1); mlist[p] = (ushort)(tid + 1024); }
  __syncthreads();  // cursors (keys alias) dead after this point
  // per-wave component scans
  int lane = tid & 63;
  while (true) {
    int c = 0;
    if (lane == 0) c = atomicAdd(&comp_head, 1);
    c = __shfl(c, 0);
    if (c >= nroots) break;
    int r = roots[c];
    int moff = off_r[r];
    int k = cnt_r[r];
    for (int step = 0; step < k; step++) {
      int kcur = k - step;
      float bestv = -1.0f; int bestj = 0x7FFFFFFF; int bestp = -1;
      for (int p = lane; p < kcur; p += 64) {
        int j = mlist[moff + p];
        float v = s_lds[j];
        if (v > bestv || (v == bestv && j < bestj)) { bestv = v; bestj = j; bestp = p; }
      }
      float gmax = wave_max_f32_bcast(bestv);
      int cand = (bestv == gmax) ? bestj : 0x7FFFFFFF;
      int bj = wave_min_i32_bcast(cand);
      if (bestj == bj && bestp >= 0) {  // unique owner lane
        mlist[moff + bestp] = mlist[moff + kcur - 1];  // swap-remove
        keys[bj] = (((ull)(uint)__float_as_int(gmax)) << 32) | (ull)(uint)(2047 - bj);
        s_lds[bj] = -1.0f;
      }
      asm volatile("s_waitcnt lgkmcnt(0)" ::: "memory");
      if (gmax > 0.001f) {
        uint base = rowptr[bj], ne = rowcnt[bj];
        for (uint e = lane; e < ne; e += 64) {
          ull ed = edges[base + e];
          int col = (int)(ed & 0xFFFFFFFFull);
          float w = __uint_as_float((uint)(ed >> 32));
          s_lds[col] *= w;  // cols distinct; selected targets are <0, harmless
        }
      }
      asm volatile("s_waitcnt lgkmcnt(0)" ::: "memory");
    }
  }
  __syncthreads();
  // bitonic sort keys descending (value desc, then index asc via 2047-j in low bits)
  for (int k2 = 2; k2 <= N; k2 <<= 1) {
    for (int jj = k2 >> 1; jj > 0; jj >>= 1) {
      int p = tid;
      int i1 = ((p & ~(jj - 1)) << 1) | (p & (jj - 1));
      int i2 = i1 | jj;
      ull a = keys[i1], b = keys[i2];
      bool up = ((i1 & k2) == 0);
      if (up ? (a < b) : (a > b)) { keys[i1] = b; keys[i2] = a; }
      __syncthreads();
    }
  }
#pragma unroll
  for (int h = 0; h < 2; h++) {
    int r = tid + 1024 * h;
    ull key = keys[r];
    int j = 2047 - (int)(uint)(key & 0xFFFFFFFFull);
    float v = __uint_as_float((uint)(key >> 32));
    out[r] = (float)j;
    out[N + r] = (v > 0.001f) ? 1.0f : 0.0f;
    out[2 * N + r] = v;
  }
}

// Tiny-ws fallback (never expected in practice).
__global__ __launch_bounds__(1024) void scan_fly(const float* __restrict__ prep,
                                                 const float* __restrict__ scores,
                                                 float* __restrict__ out) {
  __shared__ float sc[N];
  __shared__ unsigned char sel[N];
  __shared__ float rv[16];
  __shared__ int ri[16];
  int tid = threadIdx.x;
  sc[tid] = scores[tid];
  sc[tid + 1024] = scores[tid + 1024];
  sel[tid] = 0;
  sel[tid + 1024] = 0;
  __syncthreads();
  const float NINF = -__builtin_inff();
  for (int t = 0; t < N; ++t) {
    float v0 = sel[tid] ? NINF : sc[tid];
    float v1 = sel[tid + 1024] ? NINF : sc[tid + 1024];
    float bv; int bi;
    if (v0 >= v1) { bv = v0; bi = tid; } else { bv = v1; bi = tid + 1024; }
#pragma unroll
    for (int off = 32; off > 0; off >>= 1) {
      float ov = __shfl_down(bv, off);
      int oi = __shfl_down(bi, off);
      if (ov > bv || (ov == bv && oi < bi)) { bv = ov; bi = oi; }
    }
    if ((tid & 63) == 0) { rv[tid >> 6] = bv; ri[tid >> 6] = bi; }
    __syncthreads();
    float mv = rv[0]; int mi = ri[0];
#pragma unroll
    for (int k = 1; k < 16; k++) {
      float ov = rv[k]; int oi = ri[k];
      if (ov > mv || (ov == mv && oi < mi)) { mv = ov; mi = oi; }
    }
    if (tid == 0) {
      out[t] = (float)mi;
      out[N + t] = (mv > 0.001f) ? 1.0f : 0.0f;
      out[2 * N + t] = mv;
    }
    if (tid == (mi & 1023)) sel[mi] = 1;
    if (mv > 0.001f) {
      const float* Pm = prep + mi * 16;
#pragma unroll
      for (int half = 0; half < 2; half++) {
        int j = tid + half * 1024;
        if (!sel[j]) {
          const float* Pj = prep + j * 16;
          float dx = Pm[8] - Pj[8], dy = Pm[9] - Pj[9];
          float rr = Pm[15] + Pj[15] + 1.0f;
          float w = 1.0f;
          if (dx * dx + dy * dy <= rr * rr) w = pair_weight(Pm, Pj);
          sc[j] *= w;
        }
      }
    }
    __syncthreads();
  }
}

extern "C" void kernel_launch(void* const* d_in, const int* in_sizes, int n_in,
                              void* d_out, int out_size, void* d_ws, size_t ws_size,
                              hipStream_t stream) {
  const float* boxes = (const float*)d_in[0];
  const float* scores = (const float*)d_in[1];
  if (n_in >= 2 && in_sizes[0] == N && in_sizes[1] == 5 * N) {
    boxes = (const float*)d_in[1];
    scores = (const float*)d_in[0];
  }
  float* out = (float*)d_out;
  char* ws = (char*)d_ws;
  uint* counter = (uint*)ws;          // ctrs[0]
  uint* ecursor = (uint*)(ws + 64);   // ctrs[16]
  uint* eflag = (uint*)(ws + 128);    // ctrs[32]
  float* prep = (float*)(ws + PREP_OFF);

  if (ws_size >= NEED_BIG) {
    uint* pairs = (uint*)(ws + PAIRS_OFF);
    ull* edges = (ull*)(ws + PAIRS_OFF);  // reuses pairs region after interB
    uint* rowptr = (uint*)(ws + RPTR_OFF);
    uint* rowcnt = (uint*)(ws + RCNT_OFF);
    float* W = (float*)(ws + W_OFF_BIG);
    prep_kernel<<<8, 256, 0, stream>>>(boxes, prep, counter);
    pairs_kernel<<<16384, 256, 0, stream>>>(prep, pairs, counter, W);
    interB_kernel<<<CAP / 64, 64, 0, stream>>>(prep, pairs, counter, W);
    csr_build<<<2048, 256, 0, stream>>>(W, edges, rowptr, rowcnt, ecursor, eflag);
    comp_scan<<<1, 1024, 0, stream>>>(scores, edges, rowptr, rowcnt, eflag, W, 0, out);
  } else if (ws_size >= NEED_SMALL) {
    float* W = (float*)(ws + W_OFF_SMALL);
    prep_kernel<<<8, 256, 0, stream>>>(boxes, prep, counter);
    inter_dense<<<65536, 64, 0, stream>>>(prep, W);
    comp_scan<<<1, 1024, 0, stream>>>(scores, (const ull*)W, (const uint*)W, (const uint*)W,
                                      counter, W, 1, out);
  } else {
    prep_kernel<<<8, 256, 0, stream>>>(boxes, prep, counter);
    scan_fly<<<1, 1024, 0, stream>>>(prep, scores, out);
  }
}

// Round 12
// 3369.331 us; speedup vs baseline: 1.2392x; 1.2392x over previous
//
#include <hip/hip_runtime.h>
#include <math.h>

#define N 2048
#define PSTRIDE 24
#define CCAP (1u << 20)
#define ECAP (1u << 19)

typedef unsigned int uint;
typedef unsigned short ushort;
typedef unsigned long long ull;

// ws layout (bytes):
#define CTR_OFF   0        // ccnt@0, ecnt@64, mcount@128
#define PREP_OFF  256      // 2048*24 f32 = 196608
#define CAND_OFF  196864   // u32[CCAP] = 4MB
#define ETMP_OFF  4391168  // u64[ECAP] = 4MB
#define ECSR_OFF  8585472  // u64[ECAP] = 4MB
#define RINF_OFF  12779776 // u32[2048] rowcnt -> packed (ptr|cnt<<20)
#define CUR_OFF   12787968 // u32[2048]
#define MARK_OFF  12796160 // u32[2048]
#define GCM_OFF   12804352 // u32[2048] col -> member idx
#define MLIST_OFF 12812544 // ushort[2048]
#define KOUT_OFF  12816640 // u64[2048]
#define NEED      12833024ull

// ---------- DPP wave-64 reductions (proven in rounds 10/11) ----------
__device__ __forceinline__ uint wave_umax_bcast(uint v) {
  int x = (int)v;
  int t;
  t = __builtin_amdgcn_update_dpp(0, x, 0x111, 0xF, 0xF, false); x = (int)((uint)x > (uint)t ? (uint)x : (uint)t);
  t = __builtin_amdgcn_update_dpp(0, x, 0x112, 0xF, 0xF, false); x = (int)((uint)x > (uint)t ? (uint)x : (uint)t);
  t = __builtin_amdgcn_update_dpp(0, x, 0x114, 0xF, 0xF, false); x = (int)((uint)x > (uint)t ? (uint)x : (uint)t);
  t = __builtin_amdgcn_update_dpp(0, x, 0x118, 0xF, 0xF, false); x = (int)((uint)x > (uint)t ? (uint)x : (uint)t);
  t = __builtin_amdgcn_update_dpp(0, x, 0x142, 0xF, 0xF, false); x = (int)((uint)x > (uint)t ? (uint)x : (uint)t);
  t = __builtin_amdgcn_update_dpp(0, x, 0x143, 0xF, 0xF, false); x = (int)((uint)x > (uint)t ? (uint)x : (uint)t);
  return (uint)__builtin_amdgcn_readlane(x, 63);
}
__device__ __forceinline__ uint wave_or_bcast(uint v) {
  int x = (int)v;
  int t;
  t = __builtin_amdgcn_update_dpp(0, x, 0x111, 0xF, 0xF, false); x |= t;
  t = __builtin_amdgcn_update_dpp(0, x, 0x112, 0xF, 0xF, false); x |= t;
  t = __builtin_amdgcn_update_dpp(0, x, 0x114, 0xF, 0xF, false); x |= t;
  t = __builtin_amdgcn_update_dpp(0, x, 0x118, 0xF, 0xF, false); x |= t;
  t = __builtin_amdgcn_update_dpp(0, x, 0x142, 0xF, 0xF, false); x |= t;
  t = __builtin_amdgcn_update_dpp(0, x, 0x143, 0xF, 0xF, false); x |= t;
  return (uint)__builtin_amdgcn_readlane(x, 63);
}

// Per-box precompute (stride 24): corners, center, cos/sin, half-extents, area,
// radius, AABB half-extents. Also zeroes counters / rowcnt / mark.
__global__ __launch_bounds__(256) void prep_kernel(const float* __restrict__ boxes,
                                                   float* __restrict__ prep,
                                                   uint* __restrict__ ctrs,
                                                   uint* __restrict__ rowcnt,
                                                   uint* __restrict__ mark) {
#pragma clang fp contract(off)
  int i = blockIdx.x * 256 + threadIdx.x;
  if (blockIdx.x == 0 && threadIdx.x < 3) ctrs[threadIdx.x * 16] = 0u;
  if (i >= N) return;
  rowcnt[i] = 0u;
  mark[i] = 0u;
  float xc = boxes[i * 5 + 0], yc = boxes[i * 5 + 1];
  float w = boxes[i * 5 + 2], h = boxes[i * 5 + 3], th = boxes[i * 5 + 4];
  float t = th * 0.017453292519943295f;
  float c = (float)cos((double)t);
  float s = (float)sin((double)t);
  float w2 = w * 0.5f, h2 = h * 0.5f;
  float lx[4] = {-w2, w2, w2, -w2};
  float ly[4] = {-h2, -h2, h2, h2};
  float* P = prep + i * PSTRIDE;
#pragma unroll
  for (int k = 0; k < 4; k++) {
    P[k * 2 + 0] = (xc + lx[k] * c) - ly[k] * s;
    P[k * 2 + 1] = (yc + lx[k] * s) + ly[k] * c;
  }
  P[8] = xc; P[9] = yc; P[10] = c; P[11] = s; P[12] = w2; P[13] = h2;
  P[14] = w * h;
  P[15] = sqrtf(w2 * w2 + h2 * h2);
  P[16] = w2 * fabsf(c) + h2 * fabsf(s) + 1e-4f;  // AABB half-extents (inflated)
  P[17] = w2 * fabsf(s) + h2 * fabsf(c) + 1e-4f;
}

// Candidate filter: AABB-overlap IoU upper bound with conservative slack.
// iou <= Iub/(aa-Iub) (monotone); drop iff 13*Iub <= 2.99*aa  =>  true iou < 0.3
// with margin >> all f32/eps errors => w == 1 exactly => prune is bit-exact.
__global__ __launch_bounds__(256) void cand_kernel(const float* __restrict__ prep,
                                                   uint* __restrict__ cand,
                                                   uint* __restrict__ ccnt) {
  uint gid = blockIdx.x * 256u + threadIdx.x;
  uint i = gid >> 11, j = gid & 2047u;
  const float* Pi = prep + i * PSTRIDE;
  const float* Pj = prep + j * PSTRIDE;
  float ox = (Pi[16] + Pj[16]) - fabsf(Pi[8] - Pj[8]);
  float oy = (Pi[17] + Pj[17]) - fabsf(Pi[9] - Pj[9]);
  bool keep = (i != j) && (ox > 0.0f) && (oy > 0.0f);
  if (keep) {
    float aa = Pi[14] + Pj[14];
    float iub = fminf(ox * oy, fminf(Pi[14], Pj[14]));
    keep = (13.0f * iub > 2.99f * aa);
  }
  ull m = __ballot(keep);
  if (m == 0ull) return;
  int lane = (int)(threadIdx.x & 63u);
  int leader = __ffsll((long long)m) - 1;
  uint base = 0;
  if (lane == leader) base = atomicAdd(ccnt, (uint)__popcll(m));
  base = (uint)__shfl((int)base, leader);
  if (keep) {
    uint pos = base + (uint)__popcll(m & ((1ull << lane) - 1ull));
    if (pos < CCAP) cand[pos] = (i << 11) | j;
  }
}

// Rotated-rect intersection weight, op-for-op fp32 mirror of the reference
// (double-eval trig/atan2 = correctly-rounded f32; proven bit-exact r8-r11).
__device__ float pair_weight(const float* __restrict__ Pi, const float* __restrict__ Pj) {
#pragma clang fp contract(off)
  float ax[4], ay[4], bx[4], by[4];
#pragma unroll
  for (int k = 0; k < 4; k++) {
    ax[k] = Pi[2 * k]; ay[k] = Pi[2 * k + 1];
    bx[k] = Pj[2 * k]; by[k] = Pj[2 * k + 1];
  }
  float ptsx[24], ptsy[24];
  bool msk[24];
#pragma unroll
  for (int e = 0; e < 4; e++) {
    float Ax = ax[e], Ay = ay[e];
    float BAx = ax[(e + 1) & 3] - Ax, BAy = ay[(e + 1) & 3] - Ay;
#pragma unroll
    for (int f = 0; f < 4; f++) {
      float Cx = bx[f], Cy = by[f];
      float DCx = bx[(f + 1) & 3] - Cx, DCy = by[(f + 1) & 3] - Cy;
      float CAx = Cx - Ax, CAy = Cy - Ay;
      float den = BAx * DCy - BAy * DCx;
      bool dok = fabsf(den) > 1e-12f;
      float dens = dok ? den : 1.0f;
      float t = (CAx * DCy - CAy * DCx) / dens;
      float u = (CAx * BAy - CAy * BAx) / dens;
      int id = e * 4 + f;
      ptsx[id] = Ax + t * BAx;
      ptsy[id] = Ay + t * BAy;
      msk[id] = dok && (t >= 0.0f) && (t <= 1.0f) && (u >= 0.0f) && (u <= 1.0f);
    }
  }
  float xcj = Pj[8], ycj = Pj[9], cj = Pj[10], sj = Pj[11], w2j = Pj[12], h2j = Pj[13];
  float xci = Pi[8], yci = Pi[9], ci = Pi[10], si = Pi[11], w2i = Pi[12], h2i = Pi[13];
#pragma unroll
  for (int k = 0; k < 4; k++) {
    float dx = ax[k] - xcj, dy = ay[k] - ycj;
    float xl = dx * cj + dy * sj;
    float yl = -dx * sj + dy * cj;
    ptsx[16 + k] = ax[k]; ptsy[16 + k] = ay[k];
    msk[16 + k] = (fabsf(xl) <= w2j + 1e-5f) && (fabsf(yl) <= h2j + 1e-5f);
  }
#pragma unroll
  for (int k = 0; k < 4; k++) {
    float dx = bx[k] - xci, dy = by[k] - yci;
    float xl = dx * ci + dy * si;
    float yl = -dx * si + dy * ci;
    ptsx[20 + k] = bx[k]; ptsy[20 + k] = by[k];
    msk[20 + k] = (fabsf(xl) <= w2i + 1e-5f) && (fabsf(yl) <= h2i + 1e-5f);
  }
  int cnt = 0;
  float sx = 0.f, sy = 0.f;
#pragma unroll
  for (int k = 0; k < 24; k++) {
    if (msk[k]) { cnt++; sx += ptsx[k]; sy += ptsy[k]; }
  }
  float fc = (float)(cnt > 1 ? cnt : 1);
  float ctx = sx / fc, cty = sy / fc;
  float ang[32], px[32], py[32];
  int idp[32];
#pragma unroll
  for (int k = 0; k < 24; k++) {
    float rx = ptsx[k] - ctx, ry = ptsy[k] - cty;
    px[k] = rx; py[k] = ry; idp[k] = k;
    ang[k] = msk[k] ? (float)atan2((double)ry, (double)rx) : 1.0e3f;
  }
#pragma unroll
  for (int k = 24; k < 32; k++) { ang[k] = 1.0e30f; px[k] = 0.f; py[k] = 0.f; idp[k] = k; }
#pragma unroll
  for (int k = 2; k <= 32; k <<= 1) {
#pragma unroll
    for (int j = k >> 1; j > 0; j >>= 1) {
#pragma unroll
      for (int x = 0; x < 32; x++) {
        int l = x ^ j;
        if (l > x) {
          bool up = ((x & k) == 0);
          bool gt = (ang[x] > ang[l]) || (ang[x] == ang[l] && idp[x] > idp[l]);
          if (gt == up) {
            float t0 = ang[x]; ang[x] = ang[l]; ang[l] = t0;
            float t1 = px[x]; px[x] = px[l]; px[l] = t1;
            float t2 = py[x]; py[x] = py[l]; py[l] = t2;
            int t3 = idp[x]; idp[x] = idp[l]; idp[l] = t3;
          }
        }
      }
    }
  }
  float term[24];
#pragma unroll
  for (int x = 0; x < 24; x++) {
    int nx = (x + 1 < cnt) ? x + 1 : 0;
    float cr = px[x] * py[nx] - py[x] * px[nx];
    term[x] = (x < cnt) ? cr : 0.0f;
  }
  float r[8];
#pragma unroll
  for (int j = 0; j < 8; j++) r[j] = (term[j] + term[j + 8]) + term[j + 16];
  float ssum = ((r[0] + r[1]) + (r[2] + r[3])) + ((r[4] + r[5]) + (r[6] + r[7]));
  float area = 0.5f * fabsf(ssum);
  float inter = (cnt >= 3) ? area : 0.0f;
  float iou = inter / ((Pi[14] + Pj[14] - inter) + 1e-9f);
  return (iou > 0.3f) ? (1.0f - iou) : 1.0f;
}

// Heavy geometry on candidates; emit sparse edge iff w != 1 (w==1 is an exact no-op).
__global__ __launch_bounds__(64, 2) void weight_kernel(const float* __restrict__ prep,
                                                       const uint* __restrict__ cand,
                                                       const uint* __restrict__ ccnt,
                                                       ull* __restrict__ etmp,
                                                       uint* __restrict__ ecnt,
                                                       uint* __restrict__ rowcnt,
                                                       uint* __restrict__ mark) {
  uint idx = blockIdx.x * 64u + threadIdx.x;
  uint n = *ccnt;
  if (n > CCAP) n = CCAP;
  if (idx >= n) return;
  uint pk = cand[idx];
  uint i = pk >> 11, j = pk & 2047u;
  float w = pair_weight(prep + i * PSTRIDE, prep + j * PSTRIDE);
  if (w != 1.0f) {
    uint pos = atomicAdd(ecnt, 1u);
    if (pos < ECAP) {
      etmp[pos] = (((ull)__float_as_uint(w)) << 32) | (ull)pk;
      atomicAdd(rowcnt + i, 1u);
      mark[i] = 1u;
      mark[j] = 1u;
    }
  }
}

// CSR finalize: prefix rowcnt -> packed rinfo (ptr|cnt<<20) + cursors; compact
// members (marked nodes) -> mlist/gcm/mcount. One workgroup.
__global__ __launch_bounds__(1024) void csr_fin(uint* __restrict__ rinfo,
                                                uint* __restrict__ cursor,
                                                const uint* __restrict__ mark,
                                                ushort* __restrict__ mlist,
                                                uint* __restrict__ gcm,
                                                uint* __restrict__ mcount) {
  __shared__ uint pre[N];
  __shared__ uint msh;
  int tid = threadIdx.x;
  uint c0 = rinfo[tid], c1 = rinfo[tid + 1024];
  pre[tid] = c0; pre[tid + 1024] = c1;
  if (tid == 0) msh = 0;
  __syncthreads();
  for (int d = 1; d < N; d <<= 1) {
    uint a0 = pre[tid] + ((tid >= d) ? pre[tid - d] : 0);
    uint a1 = pre[tid + 1024] + ((tid + 1024 >= d) ? pre[tid + 1024 - d] : 0);
    __syncthreads();
    pre[tid] = a0; pre[tid + 1024] = a1;
    __syncthreads();
  }
  uint p0 = pre[tid] - c0, p1 = pre[tid + 1024] - c1;
  rinfo[tid] = p0 | (c0 << 20);
  rinfo[tid + 1024] = p1 | (c1 << 20);
  cursor[tid] = p0;
  cursor[tid + 1024] = p1;
  if (mark[tid]) { uint m = atomicAdd(&msh, 1u); mlist[m] = (ushort)tid; gcm[tid] = m; }
  if (mark[tid + 1024]) { uint m = atomicAdd(&msh, 1u); mlist[m] = (ushort)(tid + 1024); gcm[tid + 1024] = m; }
  __syncthreads();
  if (tid == 0) *mcount = msh;
}

// Scatter edges into CSR slots; target stored as member index (via gcm).
__global__ __launch_bounds__(256) void escat_kernel(const ull* __restrict__ etmp,
                                                    const uint* __restrict__ ecnt,
                                                    uint* __restrict__ cursor,
                                                    const uint* __restrict__ gcm,
                                                    ull* __restrict__ ecsr) {
  uint e = blockIdx.x * 256u + threadIdx.x;
  uint n = *ecnt;
  if (n > ECAP) n = ECAP;
  if (e >= n) return;
  ull ed = etmp[e];
  uint lo = (uint)ed;
  uint i = (lo >> 11) & 2047u, j = lo & 2047u;
  uint pos = atomicAdd(cursor + i, 1u);
  ecsr[pos] = (ed & 0xFFFFFFFF00000000ull) | (ull)gcm[j];
}

// Sequential soft-NMS over MEMBERS only, ONE wave, zero barriers.
// Lane caches its max key; argmax = 2 DPP chains; decay = sparse LDS scatter;
// dirty lanes (DPP-OR mask) rebuild their cached max. Emits per-node pick-value
// keys; global order recovered by sorting (validated bit-exact in round 11).
__global__ __launch_bounds__(64) void scan_sub(const float* __restrict__ scores,
                                               const ushort* __restrict__ mlist,
                                               const uint* __restrict__ mcount,
                                               const uint* __restrict__ rinfo_g,
                                               const ull* __restrict__ ecsr,
                                               const uint* __restrict__ mark,
                                               ull* __restrict__ kout) {
#pragma clang fp contract(off)
  __shared__ ull mkey[N];
  __shared__ uint rinfo[N];
  const int lane = threadIdx.x;
  // load rinfo (2048 u32, 8/lane via uint4)
#pragma unroll
  for (int k = 0; k < 8; k++) {
    int i4 = lane + 64 * k;
    ((uint4*)rinfo)[i4] = ((const uint4*)rinfo_g)[i4];
  }
  // non-member keys straight to kout
#pragma unroll
  for (int k = 0; k < 32; k++) {
    int col = lane + 64 * k;
    if (!mark[col]) {
      uint b = __float_as_uint(scores[col]);
      kout[col] = (((ull)b) << 32) | (ull)(uint)(2048 - col);
    }
  }
  int M = (int)*mcount;
  int nslots = (M + 63) >> 6;
  ull pkey = 0; int pm = -1;
  for (int g = 0; g < nslots; g++) {
    int m = lane + 64 * g;
    if (m < M) {
      int col = (int)mlist[m];
      uint b = __float_as_uint(scores[col]);
      ull key = (((ull)b) << 32) | (ull)(uint)(2048 - col);
      mkey[m] = key;
      if (key > pkey) { pkey = key; pm = m; }
    }
  }
  asm volatile("s_waitcnt lgkmcnt(0)" ::: "memory");
  for (int t = 0; t < M; ++t) {
    uint hi = (uint)(pkey >> 32);
    uint ghi = wave_umax_bcast(hi);
    float gv = __uint_as_float(ghi);
    if (!((double)gv > 0.001)) break;  // no decays ever again (values only shrink)
    uint lo = (uint)pkey;
    uint cnd = (hi == ghi) ? lo : 0u;
    uint glo = wave_umax_bcast(cnd);
    int bj = 2048 - (int)glo;
    uint dlo = 0, dhi_m = 0;
    if (hi == ghi && lo == glo) {  // unique owner
      mkey[pm] = 0ull;
      kout[bj] = (((ull)ghi) << 32) | (ull)glo;
      if (lane < 32) dlo |= 1u << lane; else dhi_m |= 1u << (lane - 32);
      pkey = 0; pm = -1;  // will rebuild via dirty path
    }
    uint info = rinfo[bj];
    uint ptr = info & 0xFFFFFu;
    uint deg = info >> 20;
    for (uint b = 0; b < deg; b += 64) {
      uint e = b + (uint)lane;
      if (e < deg) {
        ull ed = ecsr[ptr + e];
        uint mt = (uint)ed & 2047u;
        float w = __uint_as_float((uint)(ed >> 32));
        ull ok = mkey[mt];
        float nv = __uint_as_float((uint)(ok >> 32)) * w;  // sentinel 0 stays 0
        mkey[mt] = (((ull)__float_as_uint(nv)) << 32) | (ok & 0xFFFFFFFFull);
        uint ol = mt & 63u;
        if (ol < 32) dlo |= 1u << ol; else dhi_m |= 1u << (ol - 32);
      }
    }
    asm volatile("s_waitcnt lgkmcnt(0)" ::: "memory");
    uint glo_m = wave_or_bcast(dlo);
    uint ghi_mm = wave_or_bcast(dhi_m);
    bool dirty = (lane < 32) ? ((glo_m >> lane) & 1u) : ((ghi_mm >> (lane - 32)) & 1u);
    if (dirty) {
      pkey = 0; pm = -1;
      for (int g = 0; g < nslots; g++) {
        int m = lane + 64 * g;
        if (m < M) {
          ull key = mkey[m];
          if (key > pkey) { pkey = key; pm = m; }
        }
      }
    }
  }
  asm volatile("s_waitcnt lgkmcnt(0)" ::: "memory");
  // flush remaining (unselected) members: current value IS their final rec
  for (int g = 0; g < nslots; g++) {
    int m = lane + 64 * g;
    if (m < M) {
      ull key = mkey[m];
      if (key != 0ull) {
        int col = 2048 - (int)(uint)key;
        kout[col] = key;
      }
    }
  }
}

// Sort 2048 keys descending (value desc, idx asc) and emit (order, keep, rec).
__global__ __launch_bounds__(1024) void sort_out(const ull* __restrict__ kout,
                                                 float* __restrict__ out) {
  __shared__ ull keys[N];
  int tid = threadIdx.x;
  keys[tid] = kout[tid];
  keys[tid + 1024] = kout[tid + 1024];
  __syncthreads();
  for (int k = 2; k <= N; k <<= 1) {
    for (int jj = k >> 1; jj > 0; jj >>= 1) {
      int i1 = ((tid & ~(jj - 1)) << 1) | (tid & (jj - 1));
      int i2 = i1 | jj;
      ull a = keys[i1], b = keys[i2];
      bool up = ((i1 & k) == 0);
      if (up ? (a < b) : (a > b)) { keys[i1] = b; keys[i2] = a; }
      __syncthreads();
    }
  }
#pragma unroll
  for (int h = 0; h < 2; h++) {
    int r = tid + 1024 * h;
    ull key = keys[r];
    int col = 2048 - (int)(uint)key;
    float v = __uint_as_float((uint)(key >> 32));
    out[r] = (float)col;
    out[N + r] = ((double)v > 0.001) ? 1.0f : 0.0f;
    out[2 * N + r] = v;
  }
}

// Tiny-ws fallback: on-the-fly dense scan (proven round 8 structure).
__global__ __launch_bounds__(1024) void scan_fly(const float* __restrict__ prep,
                                                 const float* __restrict__ scores,
                                                 float* __restrict__ out) {
  __shared__ float sc[N];
  __shared__ unsigned char sel[N];
  __shared__ float rv[16];
  __shared__ int ri[16];
  int tid = threadIdx.x;
  sc[tid] = scores[tid];
  sc[tid + 1024] = scores[tid + 1024];
  sel[tid] = 0;
  sel[tid + 1024] = 0;
  __syncthreads();
  const float NINF = -__builtin_inff();
  for (int t = 0; t < N; ++t) {
    float v0 = sel[tid] ? NINF : sc[tid];
    float v1 = sel[tid + 1024] ? NINF : sc[tid + 1024];
    float bv; int bi;
    if (v0 >= v1) { bv = v0; bi = tid; } else { bv = v1; bi = tid + 1024; }
#pragma unroll
    for (int off = 32; off > 0; off >>= 1) {
      float ov = __shfl_down(bv, off);
      int oi = __shfl_down(bi, off);
      if (ov > bv || (ov == bv && oi < bi)) { bv = ov; bi = oi; }
    }
    if ((tid & 63) == 0) { rv[tid >> 6] = bv; ri[tid >> 6] = bi; }
    __syncthreads();
    float mv = rv[0]; int mi = ri[0];
#pragma unroll
    for (int k = 1; k < 16; k++) {
      float ov = rv[k]; int oi = ri[k];
      if (ov > mv || (ov == mv && oi < mi)) { mv = ov; mi = oi; }
    }
    if (tid == 0) {
      out[t] = (float)mi;
      out[N + t] = (mv > 0.001f) ? 1.0f : 0.0f;
      out[2 * N + t] = mv;
    }
    if (tid == (mi & 1023)) sel[mi] = 1;
    if (mv > 0.001f) {
      const float* Pm = prep + mi * PSTRIDE;
#pragma unroll
      for (int half = 0; half < 2; half++) {
        int j = tid + half * 1024;
        if (!sel[j]) {
          const float* Pj = prep + j * PSTRIDE;
          float dx = Pm[8] - Pj[8], dy = Pm[9] - Pj[9];
          float rr = Pm[15] + Pj[15] + 1.0f;
          float w = 1.0f;
          if (dx * dx + dy * dy <= rr * rr) w = pair_weight(Pm, Pj);
          sc[j] *= w;
        }
      }
    }
    __syncthreads();
  }
}

extern "C" void kernel_launch(void* const* d_in, const int* in_sizes, int n_in,
                              void* d_out, int out_size, void* d_ws, size_t ws_size,
                              hipStream_t stream) {
  const float* boxes = (const float*)d_in[0];
  const float* scores = (const float*)d_in[1];
  if (n_in >= 2 && in_sizes[0] == N && in_sizes[1] == 5 * N) {
    boxes = (const float*)d_in[1];
    scores = (const float*)d_in[0];
  }
  float* out = (float*)d_out;
  char* ws = (char*)d_ws;
  uint* ccnt = (uint*)(ws + CTR_OFF);
  uint* ecnt = (uint*)(ws + CTR_OFF + 64);
  uint* mcount = (uint*)(ws + CTR_OFF + 128);
  float* prep = (float*)(ws + PREP_OFF);

  if (ws_size >= NEED) {
    uint* cand = (uint*)(ws + CAND_OFF);
    ull* etmp = (ull*)(ws + ETMP_OFF);
    ull* ecsr = (ull*)(ws + ECSR_OFF);
    uint* rinfo = (uint*)(ws + RINF_OFF);
    uint* cursor = (uint*)(ws + CUR_OFF);
    uint* mark = (uint*)(ws + MARK_OFF);
    uint* gcm = (uint*)(ws + GCM_OFF);
    ushort* mlist = (ushort*)(ws + MLIST_OFF);
    ull* kout = (ull*)(ws + KOUT_OFF);
    prep_kernel<<<8, 256, 0, stream>>>(boxes, prep, (uint*)ws, rinfo, mark);
    cand_kernel<<<16384, 256, 0, stream>>>(prep, cand, ccnt);
    weight_kernel<<<CCAP / 64, 64, 0, stream>>>(prep, cand, ccnt, etmp, ecnt, rinfo, mark);
    csr_fin<<<1, 1024, 0, stream>>>(rinfo, cursor, mark, mlist, gcm, mcount);
    escat_kernel<<<ECAP / 256, 256, 0, stream>>>(etmp, ecnt, cursor, gcm, ecsr);
    scan_sub<<<1, 64, 0, stream>>>(scores, mlist, mcount, rinfo, ecsr, mark, kout);
    sort_out<<<1, 1024, 0, stream>>>(kout, out);
  } else {
    prep_kernel<<<8, 256, 0, stream>>>(boxes, prep, (uint*)ws,
                                       (uint*)(ws + 256 + 196608),
                                       (uint*)(ws + 256 + 196608 + 8192));
    scan_fly<<<1, 1024, 0, stream>>>(prep, scores, out);
  }
}

// Round 13
// 2076.297 us; speedup vs baseline: 2.0110x; 1.6228x over previous
//
#include <hip/hip_runtime.h>
#include <math.h>

#define N 2048
#define PSTRIDE 24
#define CCAP (1u << 20)
#define ECAP (1u << 19)
#define ELCAP 12288u  // edges cached in LDS (96KB)

typedef unsigned int uint;
typedef unsigned short ushort;
typedef unsigned long long ull;

// ws layout (bytes):
#define CTR_OFF   0        // ccnt@0, ecnt@64, mcount@128
#define PREP_OFF  256      // 2048*24 f32
#define CAND_OFF  196864   // u32[CCAP]
#define ETMP_OFF  4391168  // u64[ECAP]
#define ECSR_OFF  8585472  // u64[ECAP]
#define RINF_OFF  12779776 // u32[2048]
#define CUR_OFF   12787968 // u32[2048]
#define MARK_OFF  12796160 // u32[2048]
#define GCM_OFF   12804352 // u32[2048]
#define MLIST_OFF 12812544 // ushort[2048]
#define KOUT_OFF  12816640 // u64[2048]
#define NEED      12833024ull

// ---------- DPP wave-64 max reduction (proven r10-r12) ----------
__device__ __forceinline__ uint wave_umax_bcast(uint v) {
  int x = (int)v;
  int t;
  t = __builtin_amdgcn_update_dpp(0, x, 0x111, 0xF, 0xF, false); x = (int)((uint)x > (uint)t ? (uint)x : (uint)t);
  t = __builtin_amdgcn_update_dpp(0, x, 0x112, 0xF, 0xF, false); x = (int)((uint)x > (uint)t ? (uint)x : (uint)t);
  t = __builtin_amdgcn_update_dpp(0, x, 0x114, 0xF, 0xF, false); x = (int)((uint)x > (uint)t ? (uint)x : (uint)t);
  t = __builtin_amdgcn_update_dpp(0, x, 0x118, 0xF, 0xF, false); x = (int)((uint)x > (uint)t ? (uint)x : (uint)t);
  t = __builtin_amdgcn_update_dpp(0, x, 0x142, 0xF, 0xF, false); x = (int)((uint)x > (uint)t ? (uint)x : (uint)t);
  t = __builtin_amdgcn_update_dpp(0, x, 0x143, 0xF, 0xF, false); x = (int)((uint)x > (uint)t ? (uint)x : (uint)t);
  return (uint)__builtin_amdgcn_readlane(x, 63);
}

// Per-box precompute + zero counters/rowcnt/mark.
__global__ __launch_bounds__(256) void prep_kernel(const float* __restrict__ boxes,
                                                   float* __restrict__ prep,
                                                   uint* __restrict__ ctrs,
                                                   uint* __restrict__ rowcnt,
                                                   uint* __restrict__ mark) {
#pragma clang fp contract(off)
  int i = blockIdx.x * 256 + threadIdx.x;
  if (blockIdx.x == 0 && threadIdx.x < 3) ctrs[threadIdx.x * 16] = 0u;
  if (i >= N) return;
  rowcnt[i] = 0u;
  mark[i] = 0u;
  float xc = boxes[i * 5 + 0], yc = boxes[i * 5 + 1];
  float w = boxes[i * 5 + 2], h = boxes[i * 5 + 3], th = boxes[i * 5 + 4];
  float t = th * 0.017453292519943295f;
  float c = (float)cos((double)t);
  float s = (float)sin((double)t);
  float w2 = w * 0.5f, h2 = h * 0.5f;
  float lx[4] = {-w2, w2, w2, -w2};
  float ly[4] = {-h2, -h2, h2, h2};
  float* P = prep + i * PSTRIDE;
#pragma unroll
  for (int k = 0; k < 4; k++) {
    P[k * 2 + 0] = (xc + lx[k] * c) - ly[k] * s;
    P[k * 2 + 1] = (yc + lx[k] * s) + ly[k] * c;
  }
  P[8] = xc; P[9] = yc; P[10] = c; P[11] = s; P[12] = w2; P[13] = h2;
  P[14] = w * h;
  P[15] = sqrtf(w2 * w2 + h2 * h2);
  P[16] = w2 * fabsf(c) + h2 * fabsf(s) + 1e-4f;
  P[17] = w2 * fabsf(s) + h2 * fabsf(c) + 1e-4f;
}

// AABB IoU-upper-bound filter (conservative slack, bit-exact prune; proven r12).
__global__ __launch_bounds__(256) void cand_kernel(const float* __restrict__ prep,
                                                   uint* __restrict__ cand,
                                                   uint* __restrict__ ccnt) {
  uint gid = blockIdx.x * 256u + threadIdx.x;
  uint i = gid >> 11, j = gid & 2047u;
  const float* Pi = prep + i * PSTRIDE;
  const float* Pj = prep + j * PSTRIDE;
  float ox = (Pi[16] + Pj[16]) - fabsf(Pi[8] - Pj[8]);
  float oy = (Pi[17] + Pj[17]) - fabsf(Pi[9] - Pj[9]);
  bool keep = (i != j) && (ox > 0.0f) && (oy > 0.0f);
  if (keep) {
    float aa = Pi[14] + Pj[14];
    float iub = fminf(ox * oy, fminf(Pi[14], Pj[14]));
    keep = (13.0f * iub > 2.99f * aa);
  }
  ull m = __ballot(keep);
  if (m == 0ull) return;
  int lane = (int)(threadIdx.x & 63u);
  int leader = __ffsll((long long)m) - 1;
  uint base = 0;
  if (lane == leader) base = atomicAdd(ccnt, (uint)__popcll(m));
  base = (uint)__shfl((int)base, leader);
  if (keep) {
    uint pos = base + (uint)__popcll(m & ((1ull << lane) - 1ull));
    if (pos < CCAP) cand[pos] = (i << 11) | j;
  }
}

// Rotated-rect intersection weight — bit-exact fp32 mirror (proven r8-r12).
__device__ float pair_weight(const float* __restrict__ Pi, const float* __restrict__ Pj) {
#pragma clang fp contract(off)
  float ax[4], ay[4], bx[4], by[4];
#pragma unroll
  for (int k = 0; k < 4; k++) {
    ax[k] = Pi[2 * k]; ay[k] = Pi[2 * k + 1];
    bx[k] = Pj[2 * k]; by[k] = Pj[2 * k + 1];
  }
  float ptsx[24], ptsy[24];
  bool msk[24];
#pragma unroll
  for (int e = 0; e < 4; e++) {
    float Ax = ax[e], Ay = ay[e];
    float BAx = ax[(e + 1) & 3] - Ax, BAy = ay[(e + 1) & 3] - Ay;
#pragma unroll
    for (int f = 0; f < 4; f++) {
      float Cx = bx[f], Cy = by[f];
      float DCx = bx[(f + 1) & 3] - Cx, DCy = by[(f + 1) & 3] - Cy;
      float CAx = Cx - Ax, CAy = Cy - Ay;
      float den = BAx * DCy - BAy * DCx;
      bool dok = fabsf(den) > 1e-12f;
      float dens = dok ? den : 1.0f;
      float t = (CAx * DCy - CAy * DCx) / dens;
      float u = (CAx * BAy - CAy * BAx) / dens;
      int id = e * 4 + f;
      ptsx[id] = Ax + t * BAx;
      ptsy[id] = Ay + t * BAy;
      msk[id] = dok && (t >= 0.0f) && (t <= 1.0f) && (u >= 0.0f) && (u <= 1.0f);
    }
  }
  float xcj = Pj[8], ycj = Pj[9], cj = Pj[10], sj = Pj[11], w2j = Pj[12], h2j = Pj[13];
  float xci = Pi[8], yci = Pi[9], ci = Pi[10], si = Pi[11], w2i = Pi[12], h2i = Pi[13];
#pragma unroll
  for (int k = 0; k < 4; k++) {
    float dx = ax[k] - xcj, dy = ay[k] - ycj;
    float xl = dx * cj + dy * sj;
    float yl = -dx * sj + dy * cj;
    ptsx[16 + k] = ax[k]; ptsy[16 + k] = ay[k];
    msk[16 + k] = (fabsf(xl) <= w2j + 1e-5f) && (fabsf(yl) <= h2j + 1e-5f);
  }
#pragma unroll
  for (int k = 0; k < 4; k++) {
    float dx = bx[k] - xci, dy = by[k] - yci;
    float xl = dx * ci + dy * si;
    float yl = -dx * si + dy * ci;
    ptsx[20 + k] = bx[k]; ptsy[20 + k] = by[k];
    msk[20 + k] = (fabsf(xl) <= w2i + 1e-5f) && (fabsf(yl) <= h2i + 1e-5f);
  }
  int cnt = 0;
  float sx = 0.f, sy = 0.f;
#pragma unroll
  for (int k = 0; k < 24; k++) {
    if (msk[k]) { cnt++; sx += ptsx[k]; sy += ptsy[k]; }
  }
  float fc = (float)(cnt > 1 ? cnt : 1);
  float ctx = sx / fc, cty = sy / fc;
  float ang[32], px[32], py[32];
  int idp[32];
#pragma unroll
  for (int k = 0; k < 24; k++) {
    float rx = ptsx[k] - ctx, ry = ptsy[k] - cty;
    px[k] = rx; py[k] = ry; idp[k] = k;
    ang[k] = msk[k] ? (float)atan2((double)ry, (double)rx) : 1.0e3f;
  }
#pragma unroll
  for (int k = 24; k < 32; k++) { ang[k] = 1.0e30f; px[k] = 0.f; py[k] = 0.f; idp[k] = k; }
#pragma unroll
  for (int k = 2; k <= 32; k <<= 1) {
#pragma unroll
    for (int j = k >> 1; j > 0; j >>= 1) {
#pragma unroll
      for (int x = 0; x < 32; x++) {
        int l = x ^ j;
        if (l > x) {
          bool up = ((x & k) == 0);
          bool gt = (ang[x] > ang[l]) || (ang[x] == ang[l] && idp[x] > idp[l]);
          if (gt == up) {
            float t0 = ang[x]; ang[x] = ang[l]; ang[l] = t0;
            float t1 = px[x]; px[x] = px[l]; px[l] = t1;
            float t2 = py[x]; py[x] = py[l]; py[l] = t2;
            int t3 = idp[x]; idp[x] = idp[l]; idp[l] = t3;
          }
        }
      }
    }
  }
  float term[24];
#pragma unroll
  for (int x = 0; x < 24; x++) {
    int nx = (x + 1 < cnt) ? x + 1 : 0;
    float cr = px[x] * py[nx] - py[x] * px[nx];
    term[x] = (x < cnt) ? cr : 0.0f;
  }
  float r[8];
#pragma unroll
  for (int j = 0; j < 8; j++) r[j] = (term[j] + term[j + 8]) + term[j + 16];
  float ssum = ((r[0] + r[1]) + (r[2] + r[3])) + ((r[4] + r[5]) + (r[6] + r[7]));
  float area = 0.5f * fabsf(ssum);
  float inter = (cnt >= 3) ? area : 0.0f;
  float iou = inter / ((Pi[14] + Pj[14] - inter) + 1e-9f);
  return (iou > 0.3f) ? (1.0f - iou) : 1.0f;
}

// Heavy geometry on candidates (grid-stride); emit sparse edge iff w != 1.
__global__ __launch_bounds__(64, 2) void weight_kernel(const float* __restrict__ prep,
                                                       const uint* __restrict__ cand,
                                                       const uint* __restrict__ ccnt,
                                                       ull* __restrict__ etmp,
                                                       uint* __restrict__ ecnt,
                                                       uint* __restrict__ rowcnt,
                                                       uint* __restrict__ mark) {
  uint n = *ccnt;
  if (n > CCAP) n = CCAP;
  for (uint idx = blockIdx.x * 64u + threadIdx.x; idx < n; idx += gridDim.x * 64u) {
    uint pk = cand[idx];
    uint i = pk >> 11, j = pk & 2047u;
    float w = pair_weight(prep + i * PSTRIDE, prep + j * PSTRIDE);
    if (w != 1.0f) {
      uint pos = atomicAdd(ecnt, 1u);
      if (pos < ECAP) {
        etmp[pos] = (((ull)__float_as_uint(w)) << 32) | (ull)pk;
        atomicAdd(rowcnt + i, 1u);
        mark[i] = 1u;
        mark[j] = 1u;
      }
    }
  }
}

// CSR finalize (proven r12).
__global__ __launch_bounds__(1024) void csr_fin(uint* __restrict__ rinfo,
                                                uint* __restrict__ cursor,
                                                const uint* __restrict__ mark,
                                                ushort* __restrict__ mlist,
                                                uint* __restrict__ gcm,
                                                uint* __restrict__ mcount) {
  __shared__ uint pre[N];
  __shared__ uint msh;
  int tid = threadIdx.x;
  uint c0 = rinfo[tid], c1 = rinfo[tid + 1024];
  pre[tid] = c0; pre[tid + 1024] = c1;
  if (tid == 0) msh = 0;
  __syncthreads();
  for (int d = 1; d < N; d <<= 1) {
    uint a0 = pre[tid] + ((tid >= d) ? pre[tid - d] : 0);
    uint a1 = pre[tid + 1024] + ((tid + 1024 >= d) ? pre[tid + 1024 - d] : 0);
    __syncthreads();
    pre[tid] = a0; pre[tid + 1024] = a1;
    __syncthreads();
  }
  uint p0 = pre[tid] - c0, p1 = pre[tid + 1024] - c1;
  rinfo[tid] = p0 | (c0 << 20);
  rinfo[tid + 1024] = p1 | (c1 << 20);
  cursor[tid] = p0;
  cursor[tid + 1024] = p1;
  if (mark[tid]) { uint m = atomicAdd(&msh, 1u); mlist[m] = (ushort)tid; gcm[tid] = m; }
  if (mark[tid + 1024]) { uint m = atomicAdd(&msh, 1u); mlist[m] = (ushort)(tid + 1024); gcm[tid + 1024] = m; }
  __syncthreads();
  if (tid == 0) *mcount = msh;
}

// Scatter edges into CSR slots; target stored as member index (grid-stride).
__global__ __launch_bounds__(256) void escat_kernel(const ull* __restrict__ etmp,
                                                    const uint* __restrict__ ecnt,
                                                    uint* __restrict__ cursor,
                                                    const uint* __restrict__ gcm,
                                                    ull* __restrict__ ecsr) {
  uint n = *ecnt;
  if (n > ECAP) n = ECAP;
  for (uint e = blockIdx.x * 256u + threadIdx.x; e < n; e += gridDim.x * 256u) {
    ull ed = etmp[e];
    uint lo = (uint)ed;
    uint i = (lo >> 11) & 2047u, j = lo & 2047u;
    uint pos = atomicAdd(cursor + i, 1u);
    ecsr[pos] = (ed & 0xFFFFFFFF00000000ull) | (ull)gcm[j];
  }
}

// Sequential soft-NMS over members, ONE wave. Incremental per-lane cached max:
// decays only decrease values, so cache is invalid ONLY if the lane's top slot
// was written (1 ds_read check). Rebuild uses 8-wide independent LDS loads.
__global__ __launch_bounds__(64) void scan_sub(const float* __restrict__ scores,
                                               const ushort* __restrict__ mlist,
                                               const uint* __restrict__ mcount,
                                               const uint* __restrict__ rinfo_g,
                                               const ull* __restrict__ ecsr,
                                               const uint* __restrict__ ecnt,
                                               const uint* __restrict__ mark,
                                               ull* __restrict__ kout) {
#pragma clang fp contract(off)
  __shared__ ull mkey[N];
  __shared__ uint rinfo[N];
  __shared__ ull eld[ELCAP];
  const int lane = threadIdx.x;
#pragma unroll
  for (int k = 0; k < 8; k++) {
    int i4 = lane + 64 * k;
    ((uint4*)rinfo)[i4] = ((const uint4*)rinfo_g)[i4];
  }
#pragma unroll
  for (int k = 0; k < 32; k++) mkey[lane + 64 * k] = 0ull;
  // non-member keys straight to kout
#pragma unroll
  for (int k = 0; k < 32; k++) {
    int col = lane + 64 * k;
    if (!mark[col]) {
      uint b = __float_as_uint(scores[col]);
      kout[col] = (((ull)b) << 32) | (ull)(uint)(2048 - col);
    }
  }
  uint E = *ecnt;
  if (E > ECAP) E = ECAP;
  bool use_lds = (E <= ELCAP);
  if (use_lds) {
    uint n4 = (E + 1) >> 1;  // uint4 count
    for (uint q = (uint)lane; q < n4; q += 64u)
      ((uint4*)eld)[q] = ((const uint4*)ecsr)[q];
  }
  int M = (int)*mcount;
  int nsl = (M + 63) >> 6;
  // fill member keys
  for (int g = 0; g < nsl; g++) {
    int m = lane + 64 * g;
    if (m < M) {
      int col = (int)mlist[m];
      uint b = __float_as_uint(scores[col]);
      mkey[m] = (((ull)b) << 32) | (ull)(uint)(2048 - col);
    }
  }
  asm volatile("s_waitcnt lgkmcnt(0) vmcnt(0)" ::: "memory");
  // initial lane max (8-wide batches, independent loads)
  ull pkey = 0; int pm = -1;
  {
    int g = 0;
    for (; g + 8 <= nsl; g += 8) {
      ull k0 = mkey[lane + 64 * (g + 0)], k1 = mkey[lane + 64 * (g + 1)];
      ull k2 = mkey[lane + 64 * (g + 2)], k3 = mkey[lane + 64 * (g + 3)];
      ull k4 = mkey[lane + 64 * (g + 4)], k5 = mkey[lane + 64 * (g + 5)];
      ull k6 = mkey[lane + 64 * (g + 6)], k7 = mkey[lane + 64 * (g + 7)];
      if (k0 > pkey) { pkey = k0; pm = lane + 64 * (g + 0); }
      if (k1 > pkey) { pkey = k1; pm = lane + 64 * (g + 1); }
      if (k2 > pkey) { pkey = k2; pm = lane + 64 * (g + 2); }
      if (k3 > pkey) { pkey = k3; pm = lane + 64 * (g + 3); }
      if (k4 > pkey) { pkey = k4; pm = lane + 64 * (g + 4); }
      if (k5 > pkey) { pkey = k5; pm = lane + 64 * (g + 5); }
      if (k6 > pkey) { pkey = k6; pm = lane + 64 * (g + 6); }
      if (k7 > pkey) { pkey = k7; pm = lane + 64 * (g + 7); }
    }
    for (; g < nsl; g++) {
      ull k = mkey[lane + 64 * g];
      if (k > pkey) { pkey = k; pm = lane + 64 * g; }
    }
  }
  for (int t = 0; t < M; ++t) {
    uint hi = (uint)(pkey >> 32);
    uint ghi = wave_umax_bcast(hi);
    if (!((double)__uint_as_float(ghi) > 0.001)) break;
    uint lo = (uint)pkey;
    uint cnd = (hi == ghi) ? lo : 0u;
    uint glo = wave_umax_bcast(cnd);
    int bj = 2048 - (int)glo;
    if (hi == ghi && lo == glo) {  // unique owner (lo unique per member)
      mkey[pm] = 0ull;
      kout[bj] = (((ull)ghi) << 32) | (ull)glo;
    }
    uint info = rinfo[bj];
    uint ptr = info & 0xFFFFFu;
    uint deg = info >> 20;
    if (use_lds) {
      for (uint e = (uint)lane; e < deg; e += 64u) {
        ull ed = eld[ptr + e];
        uint mt = (uint)ed & 2047u;
        float w = __uint_as_float((uint)(ed >> 32));
        ull ok = mkey[mt];
        float nv = __uint_as_float((uint)(ok >> 32)) * w;
        mkey[mt] = (((ull)__float_as_uint(nv)) << 32) | (ok & 0xFFFFFFFFull);
      }
    } else {
      for (uint e = (uint)lane; e < deg; e += 64u) {
        ull ed = ecsr[ptr + e];
        uint mt = (uint)ed & 2047u;
        float w = __uint_as_float((uint)(ed >> 32));
        ull ok = mkey[mt];
        float nv = __uint_as_float((uint)(ok >> 32)) * w;
        mkey[mt] = (((ull)__float_as_uint(nv)) << 32) | (ok & 0xFFFFFFFFull);
      }
    }
    asm volatile("s_waitcnt lgkmcnt(0)" ::: "memory");
    // incremental cache validity: only if my top slot changed
    bool need = false;
    if (pm >= 0) need = (mkey[pm] != pkey);
    if (need) {
      pkey = 0; pm = -1;
      int g = 0;
      for (; g + 8 <= nsl; g += 8) {
        ull k0 = mkey[lane + 64 * (g + 0)], k1 = mkey[lane + 64 * (g + 1)];
        ull k2 = mkey[lane + 64 * (g + 2)], k3 = mkey[lane + 64 * (g + 3)];
        ull k4 = mkey[lane + 64 * (g + 4)], k5 = mkey[lane + 64 * (g + 5)];
        ull k6 = mkey[lane + 64 * (g + 6)], k7 = mkey[lane + 64 * (g + 7)];
        if (k0 > pkey) { pkey = k0; pm = lane + 64 * (g + 0); }
        if (k1 > pkey) { pkey = k1; pm = lane + 64 * (g + 1); }
        if (k2 > pkey) { pkey = k2; pm = lane + 64 * (g + 2); }
        if (k3 > pkey) { pkey = k3; pm = lane + 64 * (g + 3); }
        if (k4 > pkey) { pkey = k4; pm = lane + 64 * (g + 4); }
        if (k5 > pkey) { pkey = k5; pm = lane + 64 * (g + 5); }
        if (k6 > pkey) { pkey = k6; pm = lane + 64 * (g + 6); }
        if (k7 > pkey) { pkey = k7; pm = lane + 64 * (g + 7); }
      }
      for (; g < nsl; g++) {
        ull k = mkey[lane + 64 * g];
        if (k > pkey) { pkey = k; pm = lane + 64 * g; }
      }
    }
  }
  asm volatile("s_waitcnt lgkmcnt(0)" ::: "memory");
  // flush remaining (unselected) members
  for (int g = 0; g < nsl; g++) {
    int m = lane + 64 * g;
    if (m < M) {
      ull key = mkey[m];
      if (key != 0ull) {
        int col = 2048 - (int)(uint)key;
        kout[col] = key;
      }
    }
  }
}

// Sort 2048 keys descending and emit (order, keep, rec). Proven r11/r12.
__global__ __launch_bounds__(1024) void sort_out(const ull* __restrict__ kout,
                                                 float* __restrict__ out) {
  __shared__ ull keys[N];
  int tid = threadIdx.x;
  keys[tid] = kout[tid];
  keys[tid + 1024] = kout[tid + 1024];
  __syncthreads();
  for (int k = 2; k <= N; k <<= 1) {
    for (int jj = k >> 1; jj > 0; jj >>= 1) {
      int i1 = ((tid & ~(jj - 1)) << 1) | (tid & (jj - 1));
      int i2 = i1 | jj;
      ull a = keys[i1], b = keys[i2];
      bool up = ((i1 & k) == 0);
      if (up ? (a < b) : (a > b)) { keys[i1] = b; keys[i2] = a; }
      __syncthreads();
    }
  }
#pragma unroll
  for (int h = 0; h < 2; h++) {
    int r = tid + 1024 * h;
    ull key = keys[r];
    int col = 2048 - (int)(uint)key;
    float v = __uint_as_float((uint)(key >> 32));
    out[r] = (float)col;
    out[N + r] = ((double)v > 0.001) ? 1.0f : 0.0f;
    out[2 * N + r] = v;
  }
}

// Tiny-ws fallback: on-the-fly dense scan (proven round 8 structure).
__global__ __launch_bounds__(1024) void scan_fly(const float* __restrict__ prep,
                                                 const float* __restrict__ scores,
                                                 float* __restrict__ out) {
  __shared__ float sc[N];
  __shared__ unsigned char sel[N];
  __shared__ float rv[16];
  __shared__ int ri[16];
  int tid = threadIdx.x;
  sc[tid] = scores[tid];
  sc[tid + 1024] = scores[tid + 1024];
  sel[tid] = 0;
  sel[tid + 1024] = 0;
  __syncthreads();
  const float NINF = -__builtin_inff();
  for (int t = 0; t < N; ++t) {
    float v0 = sel[tid] ? NINF : sc[tid];
    float v1 = sel[tid + 1024] ? NINF : sc[tid + 1024];
    float bv; int bi;
    if (v0 >= v1) { bv = v0; bi = tid; } else { bv = v1; bi = tid + 1024; }
#pragma unroll
    for (int off = 32; off > 0; off >>= 1) {
      float ov = __shfl_down(bv, off);
      int oi = __shfl_down(bi, off);
      if (ov > bv || (ov == bv && oi < bi)) { bv = ov; bi = oi; }
    }
    if ((tid & 63) == 0) { rv[tid >> 6] = bv; ri[tid >> 6] = bi; }
    __syncthreads();
    float mv = rv[0]; int mi = ri[0];
#pragma unroll
    for (int k = 1; k < 16; k++) {
      float ov = rv[k]; int oi = ri[k];
      if (ov > mv || (ov == mv && oi < mi)) { mv = ov; mi = oi; }
    }
    if (tid == 0) {
      out[t] = (float)mi;
      out[N + t] = (mv > 0.001f) ? 1.0f : 0.0f;
      out[2 * N + t] = mv;
    }
    if (tid == (mi & 1023)) sel[mi] = 1;
    if (mv > 0.001f) {
      const float* Pm = prep + mi * PSTRIDE;
#pragma unroll
      for (int half = 0; half < 2; half++) {
        int j = tid + half * 1024;
        if (!sel[j]) {
          const float* Pj = prep + j * PSTRIDE;
          float dx = Pm[8] - Pj[8], dy = Pm[9] - Pj[9];
          float rr = Pm[15] + Pj[15] + 1.0f;
          float w = 1.0f;
          if (dx * dx + dy * dy <= rr * rr) w = pair_weight(Pm, Pj);
          sc[j] *= w;
        }
      }
    }
    __syncthreads();
  }
}

extern "C" void kernel_launch(void* const* d_in, const int* in_sizes, int n_in,
                              void* d_out, int out_size, void* d_ws, size_t ws_size,
                              hipStream_t stream) {
  const float* boxes = (const float*)d_in[0];
  const float* scores = (const float*)d_in[1];
  if (n_in >= 2 && in_sizes[0] == N && in_sizes[1] == 5 * N) {
    boxes = (const float*)d_in[1];
    scores = (const float*)d_in[0];
  }
  float* out = (float*)d_out;
  char* ws = (char*)d_ws;
  uint* ccnt = (uint*)(ws + CTR_OFF);
  uint* ecnt = (uint*)(ws + CTR_OFF + 64);
  uint* mcount = (uint*)(ws + CTR_OFF + 128);
  float* prep = (float*)(ws + PREP_OFF);

  if (ws_size >= NEED) {
    uint* cand = (uint*)(ws + CAND_OFF);
    ull* etmp = (ull*)(ws + ETMP_OFF);
    ull* ecsr = (ull*)(ws + ECSR_OFF);
    uint* rinfo = (uint*)(ws + RINF_OFF);
    uint* cursor = (uint*)(ws + CUR_OFF);
    uint* mark = (uint*)(ws + MARK_OFF);
    uint* gcm = (uint*)(ws + GCM_OFF);
    ushort* mlist = (ushort*)(ws + MLIST_OFF);
    ull* kout = (ull*)(ws + KOUT_OFF);
    prep_kernel<<<8, 256, 0, stream>>>(boxes, prep, (uint*)ws, rinfo, mark);
    cand_kernel<<<16384, 256, 0, stream>>>(prep, cand, ccnt);
    weight_kernel<<<1024, 64, 0, stream>>>(prep, cand, ccnt, etmp, ecnt, rinfo, mark);
    csr_fin<<<1, 1024, 0, stream>>>(rinfo, cursor, mark, mlist, gcm, mcount);
    escat_kernel<<<256, 256, 0, stream>>>(etmp, ecnt, cursor, gcm, ecsr);
    scan_sub<<<1, 64, 0, stream>>>(scores, mlist, mcount, rinfo, ecsr, ecnt, mark, kout);
    sort_out<<<1, 1024, 0, stream>>>(kout, out);
  } else {
    prep_kernel<<<8, 256, 0, stream>>>(boxes, prep, (uint*)ws,
                                       (uint*)(ws + 256 + 196608),
                                       (uint*)(ws + 256 + 196608 + 8192));
    scan_fly<<<1, 1024, 0, stream>>>(prep, scores, out);
  }
}